// Round 1
// baseline (45027.982 us; speedup 1.0000x reference)
//
#include <hip/hip_runtime.h>
#include <math.h>

#define BB 4096
#define NN 256
#define FIN 15
#define HH 128
#define HH4 32
#define FOUT 6

__device__ __forceinline__ float silu_f(float z) {
    return z / (1.0f + __expf(-z));
}

__launch_bounds__(256, 2)
__global__ void stargnn_kernel(
    const float* __restrict__ x_feat,   // (B,N,FIN)
    const float* __restrict__ coords,   // (B,N,3)
    const float* __restrict__ mask,     // (B,N,1)
    const int*   __restrict__ centers,  // (B,)
    const float* __restrict__ nW1, const float* __restrict__ nb1,
    const float* __restrict__ nW2, const float* __restrict__ nb2,
    const float* __restrict__ eW1, const float* __restrict__ eb1,
    const float* __restrict__ eW2, const float* __restrict__ eb2,
    const float* __restrict__ rW1, const float* __restrict__ rb1,
    const float* __restrict__ rW2, const float* __restrict__ rb2,
    float* __restrict__ out)            // (B,FOUT)
{
    const int b   = blockIdx.x;
    const int tid = threadIdx.x;
    const int tj  = tid & 15;    // 16 column-groups of 8
    const int tn  = tid >> 4;    // 16 row-groups of 4

    // LDS layout (floats): total 15808 f32 = 63232 B
    __shared__ float smem[15808];
    float* w1s = smem;            // 15*128   = 1920
    float* h1s = smem + 1920;     // 64*132   = 8448  (padded stride 132)
    float* w2s = smem + 10368;    // 32*128   = 4096  (k-chunk of nW2)
    float* xts = smem + 14464;    // 64*15    = 960
    float* wns = smem + 15424;    // 256
    float* hcs = smem + 15680;    // 128

    // ---------------- prologue ----------------
    // stage nW1 (coalesced float4)
    for (int i = tid; i < (FIN*HH)/4; i += 256)
        ((float4*)w1s)[i] = ((const float4*)nW1)[i];

    const int c = centers[b];

    // edge MLP: one node per thread -> wns[n] = sigmoid(...) * mask^2
    {
        const float* cb = coords + (size_t)b * NN * 3;
        const float c0x = cb[c*3+0], c0y = cb[c*3+1], c0z = cb[c*3+2];
        const float dx = cb[tid*3+0] - c0x;
        const float dy = cb[tid*3+1] - c0y;
        const float dz = cb[tid*3+2] - c0z;
        const float d  = sqrtf(dx*dx + dy*dy + dz*dz);
        float s = eb2[0];
        #pragma unroll
        for (int i = 0; i < HH4; ++i) {
            float z = d * eW1[i] + eb1[i];
            s += silu_f(z) * eW2[i];
        }
        const float w = 1.0f / (1.0f + __expf(-s));
        const float m = mask[(size_t)b * NN + tid];
        wns[tid] = w * m * m;
    }

    float b1v[8], b2v[8];
    #pragma unroll
    for (int jj = 0; jj < 8; ++jj) {
        b1v[jj] = nb1[tj*8+jj];
        b2v[jj] = nb2[tj*8+jj];
    }

    float msgacc[8];
    #pragma unroll
    for (int jj = 0; jj < 8; ++jj) msgacc[jj] = 0.f;

    const float maskc = mask[(size_t)b * NN + c];

    // ---------------- main loop over 4 node-tiles of 64 ----------------
    for (int tile = 0; tile < 4; ++tile) {
        __syncthreads();   // previous tile's reads of xts/h1s complete
        const float* xb = x_feat + ((size_t)b * NN + tile*64) * FIN;
        for (int i = tid; i < (64*FIN)/4; i += 256)
            ((float4*)xts)[i] = ((const float4*)xb)[i];
        __syncthreads();   // xts ready (w1s ready since before first tile)

        // ----- layer 1: h1s[ni][j] = silu(x @ nW1 + nb1) -----
        {
            float acc[4][8];
            #pragma unroll
            for (int i = 0; i < 4; ++i)
                #pragma unroll
                for (int jj = 0; jj < 8; ++jj) acc[i][jj] = b1v[jj];

            for (int k = 0; k < FIN; ++k) {
                const float4 w0 = *(const float4*)&w1s[k*HH + tj*8];
                const float4 w1 = *(const float4*)&w1s[k*HH + tj*8 + 4];
                const float wv[8] = {w0.x,w0.y,w0.z,w0.w,w1.x,w1.y,w1.z,w1.w};
                #pragma unroll
                for (int i = 0; i < 4; ++i) {
                    const float xa = xts[(tn*4+i)*FIN + k];
                    #pragma unroll
                    for (int jj = 0; jj < 8; ++jj) acc[i][jj] += xa * wv[jj];
                }
            }
            #pragma unroll
            for (int i = 0; i < 4; ++i) {
                #pragma unroll
                for (int jj = 0; jj < 8; ++jj)
                    h1s[(tn*4+i)*132 + tj*8 + jj] = silu_f(acc[i][jj]);
            }
        }

        // ----- layer 2: acc2 = h1 @ nW2, nW2 staged in 32-row chunks -----
        float acc2[4][8];
        #pragma unroll
        for (int i = 0; i < 4; ++i)
            #pragma unroll
            for (int jj = 0; jj < 8; ++jj) acc2[i][jj] = b2v[jj];

        for (int kc = 0; kc < 4; ++kc) {
            __syncthreads();   // h1s ready (kc=0) / prev chunk reads done
            const float4* wsrc = (const float4*)(nW2 + kc*32*HH);
            for (int i = tid; i < (32*HH)/4; i += 256)
                ((float4*)w2s)[i] = wsrc[i];
            __syncthreads();   // chunk ready

            for (int kk = 0; kk < 32; ++kk) {
                const float4 w0 = *(const float4*)&w2s[kk*HH + tj*8];
                const float4 w1 = *(const float4*)&w2s[kk*HH + tj*8 + 4];
                const float wv[8] = {w0.x,w0.y,w0.z,w0.w,w1.x,w1.y,w1.z,w1.w};
                #pragma unroll
                for (int i = 0; i < 4; ++i) {
                    const float a = h1s[(tn*4+i)*132 + kc*32 + kk];
                    #pragma unroll
                    for (int jj = 0; jj < 8; ++jj) acc2[i][jj] += a * wv[jj];
                }
            }
        }

        // ----- tile epilogue: silu, weighted accumulate, center capture -----
        #pragma unroll
        for (int i = 0; i < 4; ++i) {
            const int n = tile*64 + tn*4 + i;
            const float wv = wns[n];
            const bool isC = (n == c);
            #pragma unroll
            for (int jj = 0; jj < 8; ++jj) {
                const float h2 = silu_f(acc2[i][jj]);
                msgacc[jj] += wv * h2;
                if (isC) hcs[tj*8+jj] = h2 * maskc;
            }
        }
    }

    // ---------------- reduce partials across the 16 row-groups ----------------
    __syncthreads();                 // all tile reads of w2s done; hcs written
    float* part = w2s;               // overlay: 16*128 = 2048 floats
    #pragma unroll
    for (int jj = 0; jj < 8; ++jj) part[tn*HH + tj*8+jj] = msgacc[jj];
    __syncthreads();

    float* msgs = xts;               // overlay: 128 floats
    if (tid < HH) {
        float m = hcs[tid];
        #pragma unroll
        for (int g = 0; g < 16; ++g) m += part[g*HH + tid];
        msgs[tid] = m;
    }
    __syncthreads();

    // ---------------- readout ----------------
    float* r1s = w1s;                // overlay: 128 floats
    if (tid < HH) {
        float acc = rb1[tid];
        for (int k = 0; k < HH; ++k) acc += msgs[k] * rW1[k*HH + tid];
        r1s[tid] = silu_f(acc);
    }
    __syncthreads();

    if (tid < FOUT) {
        float acc = rb2[tid];
        for (int k = 0; k < HH; ++k) acc += r1s[k] * rW2[k*FOUT + tid];
        out[(size_t)b*FOUT + tid] = acc;
    }
}

extern "C" void kernel_launch(void* const* d_in, const int* in_sizes, int n_in,
                              void* d_out, int out_size, void* d_ws, size_t ws_size,
                              hipStream_t stream) {
    const float* x_feat = (const float*)d_in[0];
    const float* coords = (const float*)d_in[1];
    const float* mask   = (const float*)d_in[2];
    const int*   ctr    = (const int*)d_in[3];
    const float* nW1 = (const float*)d_in[4];
    const float* nb1 = (const float*)d_in[5];
    const float* nW2 = (const float*)d_in[6];
    const float* nb2 = (const float*)d_in[7];
    const float* eW1 = (const float*)d_in[8];
    const float* eb1 = (const float*)d_in[9];
    const float* eW2 = (const float*)d_in[10];
    const float* eb2 = (const float*)d_in[11];
    const float* rW1 = (const float*)d_in[12];
    const float* rb1 = (const float*)d_in[13];
    const float* rW2 = (const float*)d_in[14];
    const float* rb2 = (const float*)d_in[15];
    float* out = (float*)d_out;

    stargnn_kernel<<<dim3(BB), dim3(256), 0, stream>>>(
        x_feat, coords, mask, ctr,
        nW1, nb1, nW2, nb2, eW1, eb1, eW2, eb2, rW1, rb1, rW2, rb2, out);
}

// Round 2
// 21059.155 us; speedup vs baseline: 2.1382x; 2.1382x over previous
//
#include <hip/hip_runtime.h>
#include <math.h>

#define BB 4096
#define NN 256
#define FIN 15
#define HH 128
#define HH4 32
#define FOUT 6

__device__ __forceinline__ float silu_f(float z) {
    return z / (1.0f + __expf(-z));
}

__launch_bounds__(256, 2)
__global__ void stargnn_kernel(
    const float* __restrict__ x_feat,   // (B,N,FIN)
    const float* __restrict__ coords,   // (B,N,3)
    const float* __restrict__ mask,     // (B,N,1)
    const int*   __restrict__ centers,  // (B,)
    const float* __restrict__ nW1, const float* __restrict__ nb1,
    const float* __restrict__ nW2, const float* __restrict__ nb2,
    const float* __restrict__ eW1, const float* __restrict__ eb1,
    const float* __restrict__ eW2, const float* __restrict__ eb2,
    const float* __restrict__ rW1, const float* __restrict__ rb1,
    const float* __restrict__ rW2, const float* __restrict__ rb2,
    float* __restrict__ out)            // (B,FOUT)
{
    const int b   = blockIdx.x;
    const int tid = threadIdx.x;
    const int tj  = tid & 15;    // 16 column-groups of 8
    const int tn  = tid >> 4;    // 16 row-groups of 4

    // LDS layout (floats): total 16064 f32 = 64256 B
    __shared__ float smem[16064];
    float* w1s = smem;            // 15*128   = 1920
    float* h1s = smem + 1920;     // 64*136   = 8704  (padded stride 136)
    float* w2s = smem + 10624;    // 32*128   = 4096  (k-chunk of nW2)
    float* xts = smem + 14720;    // 64*15    = 960
    float* wns = smem + 15680;    // 256
    float* hcs = smem + 15936;    // 128

    // ---------------- prologue ----------------
    for (int i = tid; i < (FIN*HH)/4; i += 256)
        ((float4*)w1s)[i] = ((const float4*)nW1)[i];

    const int c = centers[b];

    // edge MLP: one node per thread -> wns[n] = sigmoid(...) * mask^2
    {
        const float* cb = coords + (size_t)b * NN * 3;
        const float c0x = cb[c*3+0], c0y = cb[c*3+1], c0z = cb[c*3+2];
        const float dx = cb[tid*3+0] - c0x;
        const float dy = cb[tid*3+1] - c0y;
        const float dz = cb[tid*3+2] - c0z;
        const float d  = sqrtf(dx*dx + dy*dy + dz*dz);
        float s = eb2[0];
        #pragma unroll
        for (int i = 0; i < HH4; ++i) {
            float z = d * eW1[i] + eb1[i];
            s += silu_f(z) * eW2[i];
        }
        const float w = 1.0f / (1.0f + __expf(-s));
        const float m = mask[(size_t)b * NN + tid];
        wns[tid] = w * m * m;
    }

    const float4 b1A = *(const float4*)&nb1[tj*8];
    const float4 b1B = *(const float4*)&nb1[tj*8+4];
    const float4 b2A = *(const float4*)&nb2[tj*8];
    const float4 b2B = *(const float4*)&nb2[tj*8+4];

    float4 msgA = make_float4(0.f,0.f,0.f,0.f);
    float4 msgB = make_float4(0.f,0.f,0.f,0.f);

    const float maskc = mask[(size_t)b * NN + c];

    // ---------------- main loop over 4 node-tiles of 64 ----------------
    for (int tile = 0; tile < 4; ++tile) {
        __syncthreads();   // previous tile's reads of xts/h1s complete
        const float* xb = x_feat + ((size_t)b * NN + tile*64) * FIN;
        for (int i = tid; i < (64*FIN)/4; i += 256)
            ((float4*)xts)[i] = ((const float4*)xb)[i];
        __syncthreads();   // xts ready

        // ----- layer 1: h1s[ni][j] = silu(x @ nW1 + nb1) -----
        {
            float4 accA[4], accB[4];
            #pragma unroll
            for (int i = 0; i < 4; ++i) { accA[i] = b1A; accB[i] = b1B; }

            #pragma unroll
            for (int k = 0; k < FIN; ++k) {
                const float4 w0 = *(const float4*)&w1s[k*HH + tj*8];
                const float4 w1 = *(const float4*)&w1s[k*HH + tj*8 + 4];
                #pragma unroll
                for (int i = 0; i < 4; ++i) {
                    const float xa = xts[(tn*4+i)*FIN + k];
                    accA[i].x += xa*w0.x; accA[i].y += xa*w0.y;
                    accA[i].z += xa*w0.z; accA[i].w += xa*w0.w;
                    accB[i].x += xa*w1.x; accB[i].y += xa*w1.y;
                    accB[i].z += xa*w1.z; accB[i].w += xa*w1.w;
                }
            }
            #pragma unroll
            for (int i = 0; i < 4; ++i) {
                float* hp = &h1s[(tn*4+i)*136 + tj*8];
                hp[0] = silu_f(accA[i].x); hp[1] = silu_f(accA[i].y);
                hp[2] = silu_f(accA[i].z); hp[3] = silu_f(accA[i].w);
                hp[4] = silu_f(accB[i].x); hp[5] = silu_f(accB[i].y);
                hp[6] = silu_f(accB[i].z); hp[7] = silu_f(accB[i].w);
            }
        }

        // ----- layer 2: acc2 = h1 @ nW2, nW2 staged in 32-row chunks -----
        float4 accA[4], accB[4];
        #pragma unroll
        for (int i = 0; i < 4; ++i) { accA[i] = b2A; accB[i] = b2B; }

        for (int kc = 0; kc < 4; ++kc) {
            __syncthreads();   // h1s ready (kc=0) / prev chunk reads done
            const float4* wsrc = (const float4*)(nW2 + kc*32*HH);
            for (int i = tid; i < (32*HH)/4; i += 256)
                ((float4*)w2s)[i] = wsrc[i];
            __syncthreads();   // chunk ready

            for (int kk = 0; kk < 32; ++kk) {
                const float4 w0 = *(const float4*)&w2s[kk*HH + tj*8];
                const float4 w1 = *(const float4*)&w2s[kk*HH + tj*8 + 4];
                #pragma unroll
                for (int i = 0; i < 4; ++i) {
                    const float a = h1s[(tn*4+i)*136 + kc*32 + kk];
                    accA[i].x += a*w0.x; accA[i].y += a*w0.y;
                    accA[i].z += a*w0.z; accA[i].w += a*w0.w;
                    accB[i].x += a*w1.x; accB[i].y += a*w1.y;
                    accB[i].z += a*w1.z; accB[i].w += a*w1.w;
                }
            }
        }

        // ----- tile epilogue: silu, weighted accumulate, center capture -----
        #pragma unroll
        for (int i = 0; i < 4; ++i) {
            const int n = tile*64 + tn*4 + i;
            const float wv = wns[n];
            const bool isC = (n == c);
            const float hA0 = silu_f(accA[i].x), hA1 = silu_f(accA[i].y);
            const float hA2 = silu_f(accA[i].z), hA3 = silu_f(accA[i].w);
            const float hB0 = silu_f(accB[i].x), hB1 = silu_f(accB[i].y);
            const float hB2 = silu_f(accB[i].z), hB3 = silu_f(accB[i].w);
            msgA.x += wv*hA0; msgA.y += wv*hA1; msgA.z += wv*hA2; msgA.w += wv*hA3;
            msgB.x += wv*hB0; msgB.y += wv*hB1; msgB.z += wv*hB2; msgB.w += wv*hB3;
            if (isC) {
                float* hp = &hcs[tj*8];
                hp[0] = hA0*maskc; hp[1] = hA1*maskc; hp[2] = hA2*maskc; hp[3] = hA3*maskc;
                hp[4] = hB0*maskc; hp[5] = hB1*maskc; hp[6] = hB2*maskc; hp[7] = hB3*maskc;
            }
        }
    }

    // ---------------- reduce partials across the 16 row-groups ----------------
    __syncthreads();                 // all tile reads of w2s done; hcs written
    float* part = w2s;               // overlay: 16*128 = 2048 floats
    {
        float* pp = &part[tn*HH + tj*8];
        pp[0]=msgA.x; pp[1]=msgA.y; pp[2]=msgA.z; pp[3]=msgA.w;
        pp[4]=msgB.x; pp[5]=msgB.y; pp[6]=msgB.z; pp[7]=msgB.w;
    }
    __syncthreads();

    float* msgs = xts;               // overlay: 128 floats
    if (tid < HH) {
        float m = hcs[tid];
        #pragma unroll
        for (int g = 0; g < 16; ++g) m += part[g*HH + tid];
        msgs[tid] = m;
    }
    __syncthreads();

    // ---------------- readout ----------------
    float* r1s = w1s;                // overlay: 128 floats
    if (tid < HH) {
        float acc = rb1[tid];
        for (int k = 0; k < HH; ++k) acc += msgs[k] * rW1[k*HH + tid];
        r1s[tid] = silu_f(acc);
    }
    __syncthreads();

    if (tid < FOUT) {
        float acc = rb2[tid];
        for (int k = 0; k < HH; ++k) acc += r1s[k] * rW2[k*FOUT + tid];
        out[(size_t)b*FOUT + tid] = acc;
    }
}

extern "C" void kernel_launch(void* const* d_in, const int* in_sizes, int n_in,
                              void* d_out, int out_size, void* d_ws, size_t ws_size,
                              hipStream_t stream) {
    const float* x_feat = (const float*)d_in[0];
    const float* coords = (const float*)d_in[1];
    const float* mask   = (const float*)d_in[2];
    const int*   ctr    = (const int*)d_in[3];
    const float* nW1 = (const float*)d_in[4];
    const float* nb1 = (const float*)d_in[5];
    const float* nW2 = (const float*)d_in[6];
    const float* nb2 = (const float*)d_in[7];
    const float* eW1 = (const float*)d_in[8];
    const float* eb1 = (const float*)d_in[9];
    const float* eW2 = (const float*)d_in[10];
    const float* eb2 = (const float*)d_in[11];
    const float* rW1 = (const float*)d_in[12];
    const float* rb1 = (const float*)d_in[13];
    const float* rW2 = (const float*)d_in[14];
    const float* rb2 = (const float*)d_in[15];
    float* out = (float*)d_out;

    stargnn_kernel<<<dim3(BB), dim3(256), 0, stream>>>(
        x_feat, coords, mask, ctr,
        nW1, nb1, nW2, nb2, eW1, eb1, eW2, eb2, rW1, rb1, rW2, rb2, out);
}

// Round 3
// 21019.310 us; speedup vs baseline: 2.1422x; 1.0019x over previous
//
#include <hip/hip_runtime.h>
#include <math.h>

#define BB 4096
#define NN 256
#define FIN 15
#define HH 128
#define HH4 32
#define FOUT 6

__device__ __forceinline__ float silu_f(float z) {
    return z / (1.0f + __expf(-z));
}

// 8 FMAs into two named float4 accumulators (A: cols tj*8..+3, B: +4..+7)
#define FMA8(A, B, X) \
    A.x += (X)*w0.x; A.y += (X)*w0.y; A.z += (X)*w0.z; A.w += (X)*w0.w; \
    B.x += (X)*w1.x; B.y += (X)*w1.y; B.z += (X)*w1.z; B.w += (X)*w1.w;

__launch_bounds__(256, 2)
__global__ void stargnn_kernel(
    const float* __restrict__ x_feat,   // (B,N,FIN)
    const float* __restrict__ coords,   // (B,N,3)
    const float* __restrict__ mask,     // (B,N,1)
    const int*   __restrict__ centers,  // (B,)
    const float* __restrict__ nW1, const float* __restrict__ nb1,
    const float* __restrict__ nW2, const float* __restrict__ nb2,
    const float* __restrict__ eW1, const float* __restrict__ eb1,
    const float* __restrict__ eW2, const float* __restrict__ eb2,
    const float* __restrict__ rW1, const float* __restrict__ rb1,
    const float* __restrict__ rW2, const float* __restrict__ rb2,
    float* __restrict__ out)            // (B,FOUT)
{
    const int b   = blockIdx.x;
    const int tid = threadIdx.x;
    const int tj  = tid & 15;    // 16 column-groups of 8
    const int tn  = tid >> 4;    // 16 row-groups of 4

    // LDS layout (floats): total 16064 f32 = 64256 B
    __shared__ float smem[16064];
    float* w1s = smem;            // 15*128   = 1920
    float* h1s = smem + 1920;     // 64*136   = 8704  (padded stride 136)
    float* w2s = smem + 10624;    // 32*128   = 4096  (k-chunk of nW2)
    float* xts = smem + 14720;    // 64*15    = 960
    float* wns = smem + 15680;    // 256
    float* hcs = smem + 15936;    // 128

    // ---------------- prologue ----------------
    for (int i = tid; i < (FIN*HH)/4; i += 256)
        ((float4*)w1s)[i] = ((const float4*)nW1)[i];

    const int c = centers[b];

    // edge MLP: one node per thread -> wns[n] = sigmoid(...) * mask^2
    {
        const float* cb = coords + (size_t)b * NN * 3;
        const float c0x = cb[c*3+0], c0y = cb[c*3+1], c0z = cb[c*3+2];
        const float dx = cb[tid*3+0] - c0x;
        const float dy = cb[tid*3+1] - c0y;
        const float dz = cb[tid*3+2] - c0z;
        const float d  = sqrtf(dx*dx + dy*dy + dz*dz);
        float s = eb2[0];
        #pragma unroll
        for (int i = 0; i < HH4; ++i) {
            float z = d * eW1[i] + eb1[i];
            s += silu_f(z) * eW2[i];
        }
        const float w = 1.0f / (1.0f + __expf(-s));
        const float m = mask[(size_t)b * NN + tid];
        wns[tid] = w * m * m;
    }

    const float4 b1A = *(const float4*)&nb1[tj*8];
    const float4 b1B = *(const float4*)&nb1[tj*8+4];
    const float4 b2A = *(const float4*)&nb2[tj*8];
    const float4 b2B = *(const float4*)&nb2[tj*8+4];

    float4 msgA = make_float4(0.f,0.f,0.f,0.f);
    float4 msgB = make_float4(0.f,0.f,0.f,0.f);

    const float maskc = mask[(size_t)b * NN + c];

    // ---------------- main loop over 4 node-tiles of 64 ----------------
    for (int tile = 0; tile < 4; ++tile) {
        __syncthreads();   // previous tile's reads of xts/h1s complete
        const float* xb = x_feat + ((size_t)b * NN + tile*64) * FIN;
        for (int i = tid; i < (64*FIN)/4; i += 256)
            ((float4*)xts)[i] = ((const float4*)xb)[i];
        __syncthreads();   // xts ready

        // ----- layer 1: h1s[ni][j] = silu(x @ nW1 + nb1) -----
        {
            float4 aA0=b1A, aA1=b1A, aA2=b1A, aA3=b1A;
            float4 aB0=b1B, aB1=b1B, aB2=b1B, aB3=b1B;

            #pragma unroll
            for (int k = 0; k < FIN; ++k) {
                const float4 w0 = *(const float4*)&w1s[k*HH + tj*8];
                const float4 w1 = *(const float4*)&w1s[k*HH + tj*8 + 4];
                const float x0 = xts[(tn*4+0)*FIN + k];
                const float x1 = xts[(tn*4+1)*FIN + k];
                const float x2 = xts[(tn*4+2)*FIN + k];
                const float x3 = xts[(tn*4+3)*FIN + k];
                FMA8(aA0,aB0,x0)
                FMA8(aA1,aB1,x1)
                FMA8(aA2,aB2,x2)
                FMA8(aA3,aB3,x3)
            }
            #define H1STORE(i, A, B) { float* hp = &h1s[(tn*4+(i))*136 + tj*8]; \
                hp[0]=silu_f(A.x); hp[1]=silu_f(A.y); hp[2]=silu_f(A.z); hp[3]=silu_f(A.w); \
                hp[4]=silu_f(B.x); hp[5]=silu_f(B.y); hp[6]=silu_f(B.z); hp[7]=silu_f(B.w); }
            H1STORE(0,aA0,aB0)
            H1STORE(1,aA1,aB1)
            H1STORE(2,aA2,aB2)
            H1STORE(3,aA3,aB3)
        }

        // ----- layer 2: acc2 = h1 @ nW2, nW2 staged in 32-row chunks -----
        float4 cA0=b2A, cA1=b2A, cA2=b2A, cA3=b2A;
        float4 cB0=b2B, cB1=b2B, cB2=b2B, cB3=b2B;

        for (int kc = 0; kc < 4; ++kc) {
            __syncthreads();   // h1s ready (kc=0) / prev chunk reads done
            const float4* wsrc = (const float4*)(nW2 + kc*32*HH);
            for (int i = tid; i < (32*HH)/4; i += 256)
                ((float4*)w2s)[i] = wsrc[i];
            __syncthreads();   // chunk ready

            for (int kk = 0; kk < 32; ++kk) {
                const float4 w0 = *(const float4*)&w2s[kk*HH + tj*8];
                const float4 w1 = *(const float4*)&w2s[kk*HH + tj*8 + 4];
                const float a0 = h1s[(tn*4+0)*136 + kc*32 + kk];
                const float a1 = h1s[(tn*4+1)*136 + kc*32 + kk];
                const float a2 = h1s[(tn*4+2)*136 + kc*32 + kk];
                const float a3 = h1s[(tn*4+3)*136 + kc*32 + kk];
                FMA8(cA0,cB0,a0)
                FMA8(cA1,cB1,a1)
                FMA8(cA2,cB2,a2)
                FMA8(cA3,cB3,a3)
            }
        }

        // ----- tile epilogue: silu, weighted accumulate, center capture -----
        #define EPI(i, A, B) { \
            const int n = tile*64 + tn*4 + (i); \
            const float wv = wns[n]; \
            const float hA0=silu_f(A.x), hA1=silu_f(A.y), hA2=silu_f(A.z), hA3=silu_f(A.w); \
            const float hB0=silu_f(B.x), hB1=silu_f(B.y), hB2=silu_f(B.z), hB3=silu_f(B.w); \
            msgA.x+=wv*hA0; msgA.y+=wv*hA1; msgA.z+=wv*hA2; msgA.w+=wv*hA3; \
            msgB.x+=wv*hB0; msgB.y+=wv*hB1; msgB.z+=wv*hB2; msgB.w+=wv*hB3; \
            if (n == c) { float* hp = &hcs[tj*8]; \
                hp[0]=hA0*maskc; hp[1]=hA1*maskc; hp[2]=hA2*maskc; hp[3]=hA3*maskc; \
                hp[4]=hB0*maskc; hp[5]=hB1*maskc; hp[6]=hB2*maskc; hp[7]=hB3*maskc; } }
        EPI(0,cA0,cB0)
        EPI(1,cA1,cB1)
        EPI(2,cA2,cB2)
        EPI(3,cA3,cB3)
    }

    // ---------------- reduce partials across the 16 row-groups ----------------
    __syncthreads();                 // all tile reads of w2s done; hcs written
    float* part = w2s;               // overlay: 16*128 = 2048 floats
    {
        float* pp = &part[tn*HH + tj*8];
        pp[0]=msgA.x; pp[1]=msgA.y; pp[2]=msgA.z; pp[3]=msgA.w;
        pp[4]=msgB.x; pp[5]=msgB.y; pp[6]=msgB.z; pp[7]=msgB.w;
    }
    __syncthreads();

    float* msgs = xts;               // overlay: 128 floats
    if (tid < HH) {
        float m = hcs[tid];
        #pragma unroll
        for (int g = 0; g < 16; ++g) m += part[g*HH + tid];
        msgs[tid] = m;
    }
    __syncthreads();

    // ---------------- readout ----------------
    float* r1s = w1s;                // overlay: 128 floats
    if (tid < HH) {
        float acc = rb1[tid];
        for (int k = 0; k < HH; ++k) acc += msgs[k] * rW1[k*HH + tid];
        r1s[tid] = silu_f(acc);
    }
    __syncthreads();

    if (tid < FOUT) {
        float acc = rb2[tid];
        for (int k = 0; k < HH; ++k) acc += r1s[k] * rW2[k*FOUT + tid];
        out[(size_t)b*FOUT + tid] = acc;
    }
}

extern "C" void kernel_launch(void* const* d_in, const int* in_sizes, int n_in,
                              void* d_out, int out_size, void* d_ws, size_t ws_size,
                              hipStream_t stream) {
    const float* x_feat = (const float*)d_in[0];
    const float* coords = (const float*)d_in[1];
    const float* mask   = (const float*)d_in[2];
    const int*   ctr    = (const int*)d_in[3];
    const float* nW1 = (const float*)d_in[4];
    const float* nb1 = (const float*)d_in[5];
    const float* nW2 = (const float*)d_in[6];
    const float* nb2 = (const float*)d_in[7];
    const float* eW1 = (const float*)d_in[8];
    const float* eb1 = (const float*)d_in[9];
    const float* eW2 = (const float*)d_in[10];
    const float* eb2 = (const float*)d_in[11];
    const float* rW1 = (const float*)d_in[12];
    const float* rb1 = (const float*)d_in[13];
    const float* rW2 = (const float*)d_in[14];
    const float* rb2 = (const float*)d_in[15];
    float* out = (float*)d_out;

    stargnn_kernel<<<dim3(BB), dim3(256), 0, stream>>>(
        x_feat, coords, mask, ctr,
        nW1, nb1, nW2, nb2, eW1, eb1, eW2, eb2, rW1, rb1, rW2, rb2, out);
}

// Round 4
// 624.197 us; speedup vs baseline: 72.1375x; 33.6742x over previous
//
#include <hip/hip_runtime.h>
#include <math.h>

#define BB 4096
#define NN 256
#define FIN 15
#define HH 128
#define HH4 32
#define FOUT 6

__device__ __forceinline__ float silu_f(float z) {
    return z / (1.0f + __expf(-z));
}

// 8 FMAs into two named float4 accumulators (A: cols tj*8..+3, B: +4..+7)
#define FMA8(A, B, X) \
    A.x += (X)*w0.x; A.y += (X)*w0.y; A.z += (X)*w0.z; A.w += (X)*w0.w; \
    B.x += (X)*w1.x; B.y += (X)*w1.y; B.z += (X)*w1.z; B.w += (X)*w1.w;

__launch_bounds__(256)
__global__ void stargnn_kernel(
    const float* __restrict__ x_feat,   // (B,N,FIN)
    const float* __restrict__ coords,   // (B,N,3)
    const float* __restrict__ mask,     // (B,N,1)
    const int*   __restrict__ centers,  // (B,)
    const float* __restrict__ nW1, const float* __restrict__ nb1,
    const float* __restrict__ nW2, const float* __restrict__ nb2,
    const float* __restrict__ eW1, const float* __restrict__ eb1,
    const float* __restrict__ eW2, const float* __restrict__ eb2,
    const float* __restrict__ rW1, const float* __restrict__ rb1,
    const float* __restrict__ rW2, const float* __restrict__ rb2,
    float* __restrict__ out)            // (B,FOUT)
{
    const int b   = blockIdx.x;
    const int tid = threadIdx.x;
    const int tj  = tid & 15;    // 16 column-groups of 8
    const int tn  = tid >> 4;    // 16 row-groups of 4

    // Separate named LDS arrays: trivial addrspace(3) inference, 16B aligned.
    __shared__ __align__(16) float w1s[FIN*HH];    // 1920
    __shared__ __align__(16) float h1s[64*136];    // 8704 (padded stride 136)
    __shared__ __align__(16) float w2s[32*HH];     // 4096 (k-chunk of nW2; reused as partials)
    __shared__ __align__(16) float xts[64*FIN];    // 960  (reused as msg vector)
    __shared__ __align__(16) float wns[NN];        // 256
    __shared__ __align__(16) float hcs[HH];        // 128

    // ---------------- prologue ----------------
    for (int i = tid; i < (FIN*HH)/4; i += 256)
        ((float4*)w1s)[i] = ((const float4*)nW1)[i];

    const int c = centers[b];

    // edge MLP: one node per thread -> wns[n] = sigmoid(...) * mask^2
    {
        const float* cb = coords + (size_t)b * NN * 3;
        const float c0x = cb[c*3+0], c0y = cb[c*3+1], c0z = cb[c*3+2];
        const float dx = cb[tid*3+0] - c0x;
        const float dy = cb[tid*3+1] - c0y;
        const float dz = cb[tid*3+2] - c0z;
        const float d  = sqrtf(dx*dx + dy*dy + dz*dz);
        float s = eb2[0];
        #pragma unroll
        for (int i = 0; i < HH4; ++i) {
            float z = d * eW1[i] + eb1[i];
            s += silu_f(z) * eW2[i];
        }
        const float w = 1.0f / (1.0f + __expf(-s));
        const float m = mask[(size_t)b * NN + tid];
        wns[tid] = w * m * m;
    }

    const float4 b1A = *(const float4*)&nb1[tj*8];
    const float4 b1B = *(const float4*)&nb1[tj*8+4];
    const float4 b2A = *(const float4*)&nb2[tj*8];
    const float4 b2B = *(const float4*)&nb2[tj*8+4];

    float4 msgA = make_float4(0.f,0.f,0.f,0.f);
    float4 msgB = make_float4(0.f,0.f,0.f,0.f);

    const float maskc = mask[(size_t)b * NN + c];

    // ---------------- main loop over 4 node-tiles of 64 ----------------
    for (int tile = 0; tile < 4; ++tile) {
        __syncthreads();   // previous tile's reads of xts/h1s complete
        const float* xb = x_feat + ((size_t)b * NN + tile*64) * FIN;
        for (int i = tid; i < (64*FIN)/4; i += 256)
            ((float4*)xts)[i] = ((const float4*)xb)[i];
        __syncthreads();   // xts ready

        // ----- layer 1: h1s[ni][j] = silu(x @ nW1 + nb1) -----
        {
            float4 aA0=b1A, aA1=b1A, aA2=b1A, aA3=b1A;
            float4 aB0=b1B, aB1=b1B, aB2=b1B, aB3=b1B;

            #pragma unroll
            for (int k = 0; k < FIN; ++k) {
                const float4 w0 = *(const float4*)&w1s[k*HH + tj*8];
                const float4 w1 = *(const float4*)&w1s[k*HH + tj*8 + 4];
                const float x0 = xts[(tn*4+0)*FIN + k];
                const float x1 = xts[(tn*4+1)*FIN + k];
                const float x2 = xts[(tn*4+2)*FIN + k];
                const float x3 = xts[(tn*4+3)*FIN + k];
                FMA8(aA0,aB0,x0)
                FMA8(aA1,aB1,x1)
                FMA8(aA2,aB2,x2)
                FMA8(aA3,aB3,x3)
            }
            #define H1STORE(i, A, B) { float* hp = &h1s[(tn*4+(i))*136 + tj*8]; \
                hp[0]=silu_f(A.x); hp[1]=silu_f(A.y); hp[2]=silu_f(A.z); hp[3]=silu_f(A.w); \
                hp[4]=silu_f(B.x); hp[5]=silu_f(B.y); hp[6]=silu_f(B.z); hp[7]=silu_f(B.w); }
            H1STORE(0,aA0,aB0)
            H1STORE(1,aA1,aB1)
            H1STORE(2,aA2,aB2)
            H1STORE(3,aA3,aB3)
        }

        // ----- layer 2: acc2 = h1 @ nW2, nW2 staged in 32-row chunks -----
        float4 cA0=b2A, cA1=b2A, cA2=b2A, cA3=b2A;
        float4 cB0=b2B, cB1=b2B, cB2=b2B, cB3=b2B;

        for (int kc = 0; kc < 4; ++kc) {
            __syncthreads();   // h1s ready (kc=0) / prev chunk reads done
            const float4* wsrc = (const float4*)(nW2 + kc*32*HH);
            for (int i = tid; i < (32*HH)/4; i += 256)
                ((float4*)w2s)[i] = wsrc[i];
            __syncthreads();   // chunk ready

            #pragma unroll 4
            for (int kk = 0; kk < 32; ++kk) {
                const float4 w0 = *(const float4*)&w2s[kk*HH + tj*8];
                const float4 w1 = *(const float4*)&w2s[kk*HH + tj*8 + 4];
                const float a0 = h1s[(tn*4+0)*136 + kc*32 + kk];
                const float a1 = h1s[(tn*4+1)*136 + kc*32 + kk];
                const float a2 = h1s[(tn*4+2)*136 + kc*32 + kk];
                const float a3 = h1s[(tn*4+3)*136 + kc*32 + kk];
                FMA8(cA0,cB0,a0)
                FMA8(cA1,cB1,a1)
                FMA8(cA2,cB2,a2)
                FMA8(cA3,cB3,a3)
            }
        }

        // ----- tile epilogue: silu, weighted accumulate, center capture -----
        #define EPI(i, A, B) { \
            const int n = tile*64 + tn*4 + (i); \
            const float wv = wns[n]; \
            const float hA0=silu_f(A.x), hA1=silu_f(A.y), hA2=silu_f(A.z), hA3=silu_f(A.w); \
            const float hB0=silu_f(B.x), hB1=silu_f(B.y), hB2=silu_f(B.z), hB3=silu_f(B.w); \
            msgA.x+=wv*hA0; msgA.y+=wv*hA1; msgA.z+=wv*hA2; msgA.w+=wv*hA3; \
            msgB.x+=wv*hB0; msgB.y+=wv*hB1; msgB.z+=wv*hB2; msgB.w+=wv*hB3; \
            if (n == c) { float* hp = &hcs[tj*8]; \
                hp[0]=hA0*maskc; hp[1]=hA1*maskc; hp[2]=hA2*maskc; hp[3]=hA3*maskc; \
                hp[4]=hB0*maskc; hp[5]=hB1*maskc; hp[6]=hB2*maskc; hp[7]=hB3*maskc; } }
        EPI(0,cA0,cB0)
        EPI(1,cA1,cB1)
        EPI(2,cA2,cB2)
        EPI(3,cA3,cB3)
    }

    // ---------------- reduce partials across the 16 row-groups ----------------
    __syncthreads();                 // all tile reads of w2s done; hcs written
    {
        float* pp = &w2s[tn*HH + tj*8];   // overlay: 16*128 = 2048 floats
        pp[0]=msgA.x; pp[1]=msgA.y; pp[2]=msgA.z; pp[3]=msgA.w;
        pp[4]=msgB.x; pp[5]=msgB.y; pp[6]=msgB.z; pp[7]=msgB.w;
    }
    __syncthreads();

    if (tid < HH) {                  // msg vector overlaid on xts
        float m = hcs[tid];
        #pragma unroll
        for (int g = 0; g < 16; ++g) m += w2s[g*HH + tid];
        xts[tid] = m;
    }
    __syncthreads();

    // ---------------- readout ----------------
    if (tid < HH) {                  // r1 overlaid on w1s
        float acc = rb1[tid];
        #pragma unroll 8
        for (int k = 0; k < HH; ++k) acc += xts[k] * rW1[k*HH + tid];
        w1s[tid] = silu_f(acc);
    }
    __syncthreads();

    if (tid < FOUT) {
        float acc = rb2[tid];
        #pragma unroll 8
        for (int k = 0; k < HH; ++k) acc += w1s[k] * rW2[k*FOUT + tid];
        out[(size_t)b*FOUT + tid] = acc;
    }
}

extern "C" void kernel_launch(void* const* d_in, const int* in_sizes, int n_in,
                              void* d_out, int out_size, void* d_ws, size_t ws_size,
                              hipStream_t stream) {
    const float* x_feat = (const float*)d_in[0];
    const float* coords = (const float*)d_in[1];
    const float* mask   = (const float*)d_in[2];
    const int*   ctr    = (const int*)d_in[3];
    const float* nW1 = (const float*)d_in[4];
    const float* nb1 = (const float*)d_in[5];
    const float* nW2 = (const float*)d_in[6];
    const float* nb2 = (const float*)d_in[7];
    const float* eW1 = (const float*)d_in[8];
    const float* eb1 = (const float*)d_in[9];
    const float* eW2 = (const float*)d_in[10];
    const float* eb2 = (const float*)d_in[11];
    const float* rW1 = (const float*)d_in[12];
    const float* rb1 = (const float*)d_in[13];
    const float* rW2 = (const float*)d_in[14];
    const float* rb2 = (const float*)d_in[15];
    float* out = (float*)d_out;

    stargnn_kernel<<<dim3(BB), dim3(256), 0, stream>>>(
        x_feat, coords, mask, ctr,
        nW1, nb1, nW2, nb2, eW1, eb1, eW2, eb2, rW1, rb1, rW2, rb2, out);
}

// Round 5
// 245.936 us; speedup vs baseline: 183.0879x; 2.5380x over previous
//
#include <hip/hip_runtime.h>
#include <math.h>

#define BB 4096
#define NN 256
#define FIN 15
#define HH 128
#define HH4 32
#define FOUT 6

typedef __attribute__((ext_vector_type(8))) short short8v;   // 8 bf16 in 4 VGPRs
typedef __attribute__((ext_vector_type(4))) float f32x4;

__device__ __forceinline__ float silu_f(float z) {
    return z / (1.0f + __expf(-z));
}

__device__ __forceinline__ unsigned short f2bf(float f) {
    unsigned int u = __builtin_bit_cast(unsigned int, f);
    u += 0x7FFFu + ((u >> 16) & 1u);      // round-to-nearest-even
    return (unsigned short)(u >> 16);
}

// ---------------- prep: transpose weights to bf16 [n][k] in ws ----------------
// ws layout (ushort): w1t[128][32] @0 (4096), w2t[128][128] @4096 (16384)
__global__ void prep_kernel(const float* __restrict__ nW1,
                            const float* __restrict__ nW2,
                            unsigned short* __restrict__ ws) {
    const int idx = blockIdx.x * 256 + threadIdx.x;
    if (idx < 4096) {
        const int n = idx >> 5, k = idx & 31;
        ws[idx] = (k < FIN) ? f2bf(nW1[k * HH + n]) : (unsigned short)0;
    } else if (idx < 20480) {
        const int j = idx - 4096;
        const int n = j >> 7, k = j & 127;
        ws[idx] = f2bf(nW2[k * HH + n]);
    }
}

#define MFMA16(A, B, C) __builtin_amdgcn_mfma_f32_16x16x32_bf16((A), (B), (C), 0, 0, 0)

__launch_bounds__(256)
__global__ void stargnn_kernel(
    const float* __restrict__ x_feat,   // (B,N,FIN)
    const float* __restrict__ coords,   // (B,N,3)
    const float* __restrict__ mask,     // (B,N,1)
    const int*   __restrict__ centers,  // (B,)
    const float* __restrict__ nb1, const float* __restrict__ nb2,
    const float* __restrict__ eW1, const float* __restrict__ eb1,
    const float* __restrict__ eW2, const float* __restrict__ eb2,
    const float* __restrict__ rW1, const float* __restrict__ rb1,
    const float* __restrict__ rW2, const float* __restrict__ rb2,
    const unsigned short* __restrict__ wbf,  // ws: w1t @0, w2t @4096
    float* __restrict__ out)            // (B,FOUT)
{
    const int b   = blockIdx.x;
    const int tid = threadIdx.x;
    const int wv  = tid >> 6;     // wave 0..3
    const int l   = tid & 63;     // lane
    const int lr  = l & 15;       // A-row / B-col / D-col within tile
    const int lg  = l >> 4;       // k-group / D-row-group

    const int nt0 = 2 * wv, nt1 = 2 * wv + 1;
    const int col0 = nt0 * 16 + lr, col1 = nt1 * 16 + lr;

    __shared__ __align__(16) unsigned short xbf[128 * 40];    // 10240 B
    __shared__ __align__(16) unsigned short h1bf[128 * 136];  // 34816 B
    __shared__ float wns[NN];       // per-node weight (sigmoid*mask^2)
    __shared__ float hcs[HH];       // center h (masked)
    __shared__ float msgs[HH];
    __shared__ float part[2 * HH];
    __shared__ float r1s[HH];

    const int   c     = centers[b];
    const float maskc = mask[(size_t)b * NN + c];

    // ---- zero xbf pad (cols 15..31 must be 0; write all once) ----
    for (int i = tid; i < 128 * 40; i += 256) xbf[i] = 0;

    // ---- edge MLP: wns[n] = sigmoid(silu(d@eW1+eb1)@eW2+eb2) * mask^2 ----
    {
        const float* cb = coords + (size_t)b * NN * 3;
        const float c0x = cb[c*3+0], c0y = cb[c*3+1], c0z = cb[c*3+2];
        const float dx = cb[tid*3+0] - c0x;
        const float dy = cb[tid*3+1] - c0y;
        const float dz = cb[tid*3+2] - c0z;
        const float d  = sqrtf(dx*dx + dy*dy + dz*dz);
        float s = eb2[0];
        #pragma unroll
        for (int i = 0; i < HH4; ++i) {
            float z = d * eW1[i] + eb1[i];
            s += silu_f(z) * eW2[i];
        }
        const float w = 1.0f / (1.0f + __expf(-s));
        const float m = mask[(size_t)b * NN + tid];
        wns[tid] = w * m * m;
    }

    // ---- per-lane biases ----
    const float nb1c0 = nb1[col0], nb1c1 = nb1[col1];
    const float nb2c0 = nb2[col0], nb2c1 = nb2[col1];

    // ---- B-fragments from ws (held in named registers for whole kernel) ----
    const short8v* w1tp = (const short8v*)wbf;            // [128][32] -> idx = n*4 + kg
    const short8v* w2tp = (const short8v*)(wbf + 4096);   // [128][128] -> idx = n*16 + kb*4 + kg
    const short8v b1f0 = w1tp[col0 * 4 + lg];
    const short8v b1f1 = w1tp[col1 * 4 + lg];
    const short8v b2f00 = w2tp[col0 * 16 + 0  + lg];
    const short8v b2f01 = w2tp[col0 * 16 + 4  + lg];
    const short8v b2f02 = w2tp[col0 * 16 + 8  + lg];
    const short8v b2f03 = w2tp[col0 * 16 + 12 + lg];
    const short8v b2f10 = w2tp[col1 * 16 + 0  + lg];
    const short8v b2f11 = w2tp[col1 * 16 + 4  + lg];
    const short8v b2f12 = w2tp[col1 * 16 + 8  + lg];
    const short8v b2f13 = w2tp[col1 * 16 + 12 + lg];

    float macc0 = 0.f, macc1 = 0.f;
    const f32x4 zacc = {0.f, 0.f, 0.f, 0.f};

    // ================= two halves of 128 nodes =================
    for (int half = 0; half < 2; ++half) {
        // ---- stage x -> bf16 [128][40] (cols 0..14; 15..31 stay zero) ----
        const float* xg = x_feat + ((size_t)b * NN + half * 128) * FIN;
        for (int i = tid; i < 128 * FIN; i += 256) {
            const int node = i / FIN;
            const int k    = i - node * FIN;
            xbf[node * 40 + k] = f2bf(xg[i]);
        }
        __syncthreads();   // xbf ready; also fences prev-half h1bf reads & wns (half0)

        // ---- layer 1 MFMA: h1 = silu(x @ nW1 + nb1) -> h1bf[128][136] ----
        #pragma unroll
        for (int mt = 0; mt < 8; ++mt) {
            const short8v a = *(const short8v*)&xbf[(mt * 16 + lr) * 40 + lg * 8];
            f32x4 d0 = MFMA16(a, b1f0, zacc);
            f32x4 d1 = MFMA16(a, b1f1, zacc);
            #define H1W(r) { \
                const int row = mt * 16 + lg * 4 + (r); \
                h1bf[row * 136 + col0] = f2bf(silu_f(d0[r] + nb1c0)); \
                h1bf[row * 136 + col1] = f2bf(silu_f(d1[r] + nb1c1)); }
            H1W(0) H1W(1) H1W(2) H1W(3)
            #undef H1W
        }
        __syncthreads();   // h1bf ready

        // ---- layer 2 MFMA + epilogue ----
        #pragma unroll
        for (int mt = 0; mt < 8; ++mt) {
            const unsigned short* arow = &h1bf[(mt * 16 + lr) * 136 + lg * 8];
            const short8v a0 = *(const short8v*)(arow);
            const short8v a1 = *(const short8v*)(arow + 32);
            const short8v a2 = *(const short8v*)(arow + 64);
            const short8v a3 = *(const short8v*)(arow + 96);
            f32x4 acc0 = zacc, acc1 = zacc;
            acc0 = MFMA16(a0, b2f00, acc0);
            acc0 = MFMA16(a1, b2f01, acc0);
            acc0 = MFMA16(a2, b2f02, acc0);
            acc0 = MFMA16(a3, b2f03, acc0);
            acc1 = MFMA16(a0, b2f10, acc1);
            acc1 = MFMA16(a1, b2f11, acc1);
            acc1 = MFMA16(a2, b2f12, acc1);
            acc1 = MFMA16(a3, b2f13, acc1);

            #define EPIR(r) { \
                const int n = half * 128 + mt * 16 + lg * 4 + (r); \
                const float mw = wns[n]; \
                const float h20 = silu_f(acc0[r] + nb2c0); \
                const float h21 = silu_f(acc1[r] + nb2c1); \
                macc0 += mw * h20; \
                macc1 += mw * h21; \
                if (n == c) { hcs[col0] = h20 * maskc; hcs[col1] = h21 * maskc; } }
            EPIR(0) EPIR(1) EPIR(2) EPIR(3)
            #undef EPIR
        }
        __syncthreads();   // h1bf reads done before next half overwrites
    }

    // ---- reduce msg across row-groups (lanes xor 16, 32) ----
    macc0 += __shfl_xor(macc0, 16);
    macc0 += __shfl_xor(macc0, 32);
    macc1 += __shfl_xor(macc1, 16);
    macc1 += __shfl_xor(macc1, 32);
    if (lg == 0) {
        msgs[col0] = macc0;
        msgs[col1] = macc1;
    }
    __syncthreads();

    if (tid < HH) msgs[tid] += hcs[tid];   // + h_center
    __syncthreads();

    // ---- readout layer 1 (f32 VALU, split-K over 2 half-waves) ----
    {
        const int j  = tid & 127;
        const int kh = tid >> 7;
        float acc = 0.f;
        #pragma unroll 8
        for (int k = kh * 64; k < kh * 64 + 64; ++k)
            acc += msgs[k] * rW1[k * HH + j];
        part[kh * HH + j] = acc;
    }
    __syncthreads();
    if (tid < HH) r1s[tid] = silu_f(part[tid] + part[HH + tid] + rb1[tid]);
    __syncthreads();

    if (tid < FOUT) {
        float acc = rb2[tid];
        #pragma unroll 8
        for (int k = 0; k < HH; ++k) acc += r1s[k] * rW2[k * FOUT + tid];
        out[(size_t)b * FOUT + tid] = acc;
    }
}

extern "C" void kernel_launch(void* const* d_in, const int* in_sizes, int n_in,
                              void* d_out, int out_size, void* d_ws, size_t ws_size,
                              hipStream_t stream) {
    const float* x_feat = (const float*)d_in[0];
    const float* coords = (const float*)d_in[1];
    const float* mask   = (const float*)d_in[2];
    const int*   ctr    = (const int*)d_in[3];
    const float* nW1 = (const float*)d_in[4];
    const float* nb1 = (const float*)d_in[5];
    const float* nW2 = (const float*)d_in[6];
    const float* nb2 = (const float*)d_in[7];
    const float* eW1 = (const float*)d_in[8];
    const float* eb1 = (const float*)d_in[9];
    const float* eW2 = (const float*)d_in[10];
    const float* eb2 = (const float*)d_in[11];
    const float* rW1 = (const float*)d_in[12];
    const float* rb1 = (const float*)d_in[13];
    const float* rW2 = (const float*)d_in[14];
    const float* rb2 = (const float*)d_in[15];
    float* out = (float*)d_out;
    unsigned short* wbf = (unsigned short*)d_ws;

    prep_kernel<<<dim3(80), dim3(256), 0, stream>>>(nW1, nW2, wbf);
    stargnn_kernel<<<dim3(BB), dim3(256), 0, stream>>>(
        x_feat, coords, mask, ctr,
        nb1, nb2, eW1, eb1, eW2, eb2, rW1, rb1, rW2, rb2, wbf, out);
}

// Round 6
// 174.436 us; speedup vs baseline: 258.1351x; 1.4099x over previous
//
#include <hip/hip_runtime.h>
#include <math.h>

#define BB 4096
#define NN 256
#define FIN 15
#define HH 128
#define HH4 32
#define FOUT 6

typedef __attribute__((ext_vector_type(8))) short short8v;   // 8 bf16 in 4 VGPRs
typedef __attribute__((ext_vector_type(4))) float f32x4;

__device__ __forceinline__ float silu_f(float z) {
    return z / (1.0f + __expf(-z));
}

__device__ __forceinline__ unsigned short f2bf(float f) {
    unsigned int u = __builtin_bit_cast(unsigned int, f);
    u += 0x7FFFu + ((u >> 16) & 1u);      // round-to-nearest-even
    return (unsigned short)(u >> 16);
}

// pack 2 f32 -> 2 bf16 in one u32 (low = lo, high = hi)
__device__ __forceinline__ unsigned int cvt_pk_bf16(float lo, float hi) {
    unsigned int r;
    asm("v_cvt_pk_bf16_f32 %0, %1, %2" : "=v"(r) : "v"(lo), "v"(hi));
    return r;
}

// ---------------- prep: weights -> bf16 [n][k] in ws ----------------
// ws (ushort): w1t[128][32] @0 (k=0..14 data, 15..31 zero)
//              w2t[128][128] @4096, k PERMUTED: kp = 32*(k>>5)... inverse below
__global__ void prep_kernel(const float* __restrict__ nW1,
                            const float* __restrict__ nW2,
                            unsigned short* __restrict__ ws) {
    const int idx = blockIdx.x * 256 + threadIdx.x;
    if (idx < 4096) {
        const int n = idx >> 5, k = idx & 31;
        ws[idx] = (k < FIN) ? f2bf(nW1[k * HH + n]) : (unsigned short)0;
    } else if (idx < 20480) {
        const int j = idx - 4096;
        const int n = j >> 7, kp = j & 127;
        // inverse of colpos: kp = 32*wvc + 2*lr + half  ->  k = 32*wvc + 16*half + lr
        const int k = 32 * (kp >> 5) + 16 * (kp & 1) + ((kp & 31) >> 1);
        ws[idx] = f2bf(nW2[k * HH + n]);
    }
}

#define MFMA16(A, B, C) __builtin_amdgcn_mfma_f32_16x16x32_bf16((A), (B), (C), 0, 0, 0)

__launch_bounds__(512)
__global__ void stargnn_kernel(
    const float* __restrict__ x_feat,   // (B,N,FIN)
    const float* __restrict__ coords,   // (B,N,3)
    const float* __restrict__ mask,     // (B,N,1)
    const int*   __restrict__ centers,  // (B,)
    const float* __restrict__ nb1, const float* __restrict__ nb2,
    const float* __restrict__ eW1, const float* __restrict__ eb1,
    const float* __restrict__ eW2, const float* __restrict__ eb2,
    const float* __restrict__ rW1, const float* __restrict__ rb1,
    const float* __restrict__ rW2, const float* __restrict__ rb2,
    const unsigned short* __restrict__ wbf,  // ws: w1t @0, w2t @4096
    float* __restrict__ out)            // (B,FOUT)
{
    const int b   = blockIdx.x;
    const int tid = threadIdx.x;
    const int wv  = tid >> 6;     // wave 0..7
    const int wvc = wv & 3;       // column-pair group: cols 32*wvc .. +31
    const int rh  = wv >> 2;      // row half: rows rh*64 .. +63 (mt = rh*4..rh*4+3)
    const int l   = tid & 63;
    const int lr  = l & 15;
    const int lg  = l >> 4;

    const int col0 = wvc * 32 + lr;        // first owned column
    const int col1 = wvc * 32 + 16 + lr;   // second owned column

    __shared__ __align__(16) unsigned short xbf[128 * 40];    // 10240 B
    __shared__ __align__(16) unsigned short h1bf[128 * 136];  // 34816 B (permuted cols)
    __shared__ float wns[NN];        // w_n * mask^2 (+ center delta)
    __shared__ float msgs[HH];
    __shared__ float part[2 * HH];   // cross-rh partials
    __shared__ float part4[4 * HH];  // readout split-K partials
    __shared__ float r1s[HH];

    const int c = centers[b];

    // ---- zero xbf once (cols 15..31 must stay 0) ----
    for (int i = tid; i < (128 * 40) / 2; i += 512)
        ((unsigned int*)xbf)[i] = 0u;

    // ---- edge MLP + center-delta: wns[n] = sig(...)*m^2 + (n==c)*m ----
    if (tid < NN) {
        const float* cb = coords + (size_t)b * NN * 3;
        const float c0x = cb[c*3+0], c0y = cb[c*3+1], c0z = cb[c*3+2];
        const float dx = cb[tid*3+0] - c0x;
        const float dy = cb[tid*3+1] - c0y;
        const float dz = cb[tid*3+2] - c0z;
        const float d  = sqrtf(dx*dx + dy*dy + dz*dz);
        float s = eb2[0];
        #pragma unroll
        for (int i = 0; i < HH4; ++i) {
            float z = d * eW1[i] + eb1[i];
            s += silu_f(z) * eW2[i];
        }
        const float w = 1.0f / (1.0f + __expf(-s));
        const float m = mask[(size_t)b * NN + tid];
        wns[tid] = w * m * m + ((tid == c) ? m : 0.0f);
    }

    // ---- bias-as-C-init vectors ----
    const float nb1c0 = nb1[col0], nb1c1 = nb1[col1];
    const float nb2c0 = nb2[col0], nb2c1 = nb2[col1];
    const f32x4 b1i0 = {nb1c0, nb1c0, nb1c0, nb1c0};
    const f32x4 b1i1 = {nb1c1, nb1c1, nb1c1, nb1c1};
    const f32x4 b2i0 = {nb2c0, nb2c0, nb2c0, nb2c0};
    const f32x4 b2i1 = {nb2c1, nb2c1, nb2c1, nb2c1};

    // ---- B-fragments (named registers, whole kernel) ----
    const short8v* w1tp = (const short8v*)wbf;            // [128][32]: idx = n*4 + lg
    const short8v* w2tp = (const short8v*)(wbf + 4096);   // [128][128] perm-k: idx = n*16 + kb*4 + lg
    const short8v b1f0 = w1tp[col0 * 4 + lg];
    const short8v b1f1 = w1tp[col1 * 4 + lg];
    const short8v b2f00 = w2tp[col0 * 16 + 0  + lg];
    const short8v b2f01 = w2tp[col0 * 16 + 4  + lg];
    const short8v b2f02 = w2tp[col0 * 16 + 8  + lg];
    const short8v b2f03 = w2tp[col0 * 16 + 12 + lg];
    const short8v b2f10 = w2tp[col1 * 16 + 0  + lg];
    const short8v b2f11 = w2tp[col1 * 16 + 4  + lg];
    const short8v b2f12 = w2tp[col1 * 16 + 8  + lg];
    const short8v b2f13 = w2tp[col1 * 16 + 12 + lg];

    float macc0 = 0.f, macc1 = 0.f;
    unsigned int* h1dw = (unsigned int*)h1bf;

    // ================= two halves of 128 nodes =================
    for (int half = 0; half < 2; ++half) {
        __syncthreads();   // fences zerofill/wns (h0) and prev-half h1/xbf reads

        // ---- stage x -> bf16 [128][40] via cvt_pk (cols 0..14; 15..31 zero) ----
        {
            const int node = tid >> 2;          // 0..127
            const int kq   = tid & 3;           // k-quad 0..3
            const float* xr = x_feat + ((size_t)b * NN + half * 128 + node) * FIN + kq * 4;
            const float f0 = xr[0];
            const float f1 = xr[1];
            const float f2 = xr[2];
            const float f3 = (kq < 3) ? xr[3] : 0.0f;   // k=15 pad
            const unsigned int p0 = cvt_pk_bf16(f0, f1);
            const unsigned int p1 = cvt_pk_bf16(f2, f3);
            unsigned int* dst = (unsigned int*)&xbf[node * 40 + kq * 4];
            dst[0] = p0;
            dst[1] = p1;
        }
        __syncthreads();   // xbf ready

        // ---- layer 1: h1 = silu(x @ nW1 + nb1) -> permuted h1bf ----
        #pragma unroll 1
        for (int mi = 0; mi < 4; ++mi) {
            const int mt = rh * 4 + mi;
            const short8v a = *(const short8v*)&xbf[(mt * 16 + lr) * 40 + lg * 8];
            f32x4 d0 = MFMA16(a, b1f0, b1i0);
            f32x4 d1 = MFMA16(a, b1f1, b1i1);
            #define H1W(r) { \
                const int row = mt * 16 + lg * 4 + (r); \
                h1dw[row * 68 + 16 * wvc + lr] = cvt_pk_bf16(silu_f(d0[r]), silu_f(d1[r])); }
            H1W(0) H1W(1) H1W(2) H1W(3)
            #undef H1W
        }
        __syncthreads();   // h1bf ready

        // ---- layer 2 MFMA + epilogue ----
        #pragma unroll 1
        for (int mi = 0; mi < 4; ++mi) {
            const int mt = rh * 4 + mi;
            const unsigned short* arow = &h1bf[(mt * 16 + lr) * 136 + lg * 8];
            const short8v a0 = *(const short8v*)(arow);
            const short8v a1 = *(const short8v*)(arow + 32);
            const short8v a2 = *(const short8v*)(arow + 64);
            const short8v a3 = *(const short8v*)(arow + 96);
            f32x4 acc0 = b2i0, acc1 = b2i1;
            acc0 = MFMA16(a0, b2f00, acc0);
            acc0 = MFMA16(a1, b2f01, acc0);
            acc0 = MFMA16(a2, b2f02, acc0);
            acc0 = MFMA16(a3, b2f03, acc0);
            acc1 = MFMA16(a0, b2f10, acc1);
            acc1 = MFMA16(a1, b2f11, acc1);
            acc1 = MFMA16(a2, b2f12, acc1);
            acc1 = MFMA16(a3, b2f13, acc1);

            #define EPIR(r) { \
                const int n = half * 128 + mt * 16 + lg * 4 + (r); \
                const float mw = wns[n]; \
                macc0 += mw * silu_f(acc0[r]); \
                macc1 += mw * silu_f(acc1[r]); }
            EPIR(0) EPIR(1) EPIR(2) EPIR(3)
            #undef EPIR
        }
    }
    __syncthreads();

    // ---- reduce msg: lanes (lg) via shfl, row-halves (rh) via LDS ----
    macc0 += __shfl_xor(macc0, 16);
    macc0 += __shfl_xor(macc0, 32);
    macc1 += __shfl_xor(macc1, 16);
    macc1 += __shfl_xor(macc1, 32);
    if (lg == 0) {
        part[rh * HH + col0] = macc0;
        part[rh * HH + col1] = macc1;
    }
    __syncthreads();

    if (tid < HH) msgs[tid] = part[tid] + part[HH + tid];
    __syncthreads();

    // ---- readout layer 1 (f32 VALU, split-K over 4 quarter groups) ----
    {
        const int j  = tid & 127;
        const int kq = tid >> 7;
        float acc = 0.f;
        #pragma unroll 8
        for (int k = kq * 32; k < kq * 32 + 32; ++k)
            acc += msgs[k] * rW1[k * HH + j];
        part4[kq * HH + j] = acc;
    }
    __syncthreads();
    if (tid < HH)
        r1s[tid] = silu_f(part4[tid] + part4[HH + tid] + part4[2 * HH + tid]
                          + part4[3 * HH + tid] + rb1[tid]);
    __syncthreads();

    if (tid < FOUT) {
        float acc = rb2[tid];
        #pragma unroll 8
        for (int k = 0; k < HH; ++k) acc += r1s[k] * rW2[k * FOUT + tid];
        out[(size_t)b * FOUT + tid] = acc;
    }
}

extern "C" void kernel_launch(void* const* d_in, const int* in_sizes, int n_in,
                              void* d_out, int out_size, void* d_ws, size_t ws_size,
                              hipStream_t stream) {
    const float* x_feat = (const float*)d_in[0];
    const float* coords = (const float*)d_in[1];
    const float* mask   = (const float*)d_in[2];
    const int*   ctr    = (const int*)d_in[3];
    const float* nW1 = (const float*)d_in[4];
    const float* nb1 = (const float*)d_in[5];
    const float* nW2 = (const float*)d_in[6];
    const float* nb2 = (const float*)d_in[7];
    const float* eW1 = (const float*)d_in[8];
    const float* eb1 = (const float*)d_in[9];
    const float* eW2 = (const float*)d_in[10];
    const float* eb2 = (const float*)d_in[11];
    const float* rW1 = (const float*)d_in[12];
    const float* rb1 = (const float*)d_in[13];
    const float* rW2 = (const float*)d_in[14];
    const float* rb2 = (const float*)d_in[15];
    float* out = (float*)d_out;
    unsigned short* wbf = (unsigned short*)d_ws;

    prep_kernel<<<dim3(80), dim3(256), 0, stream>>>(nW1, nW2, wbf);
    stargnn_kernel<<<dim3(BB), dim3(512), 0, stream>>>(
        x_feat, coords, mask, ctr,
        nb1, nb2, eW1, eb1, eW2, eb2, rW1, rb1, rW2, rb2, wbf, out);
}

// Round 7
// 123.919 us; speedup vs baseline: 363.3653x; 1.4077x over previous
//
#include <hip/hip_runtime.h>
#include <math.h>

#define BB 4096
#define NN 256
#define FIN 15
#define HH 128
#define HH4 32
#define FOUT 6

typedef __attribute__((ext_vector_type(8))) short short8v;   // 8 bf16 in 4 VGPRs
typedef __attribute__((ext_vector_type(4))) float f32x4;

// fast silu/sigmoid: v_exp + v_rcp (no IEEE divide sequence)
__device__ __forceinline__ float silu_f(float z) {
    return z * __builtin_amdgcn_rcpf(1.0f + __expf(-z));
}
__device__ __forceinline__ float sigm_f(float z) {
    return __builtin_amdgcn_rcpf(1.0f + __expf(-z));
}

__device__ __forceinline__ unsigned short f2bf(float f) {
    unsigned int u = __builtin_bit_cast(unsigned int, f);
    u += 0x7FFFu + ((u >> 16) & 1u);      // round-to-nearest-even
    return (unsigned short)(u >> 16);
}

// pack 2 f32 -> 2 bf16 in one u32 (low = lo, high = hi)
__device__ __forceinline__ unsigned int cvt_pk_bf16(float lo, float hi) {
    unsigned int r;
    asm("v_cvt_pk_bf16_f32 %0, %1, %2" : "=v"(r) : "v"(lo), "v"(hi));
    return r;
}

// ---------------- prep: weights -> bf16 [n][k] in ws ----------------
// ws (ushort): w1t[128][32] @0 (k=0..14 data, 15..31 zero)
//              w2t[128][128] @4096, k PERMUTED to match h1 paired-column layout
__global__ void prep_kernel(const float* __restrict__ nW1,
                            const float* __restrict__ nW2,
                            unsigned short* __restrict__ ws) {
    const int idx = blockIdx.x * 256 + threadIdx.x;
    if (idx < 4096) {
        const int n = idx >> 5, k = idx & 31;
        ws[idx] = (k < FIN) ? f2bf(nW1[k * HH + n]) : (unsigned short)0;
    } else if (idx < 20480) {
        const int j = idx - 4096;
        const int n = j >> 7, kp = j & 127;
        // inverse of colpos: kp = 32*wvc + 2*lr + half  ->  k = 32*wvc + 16*half + lr
        const int k = 32 * (kp >> 5) + 16 * (kp & 1) + ((kp & 31) >> 1);
        ws[idx] = f2bf(nW2[k * HH + n]);
    }
}

#define MFMA16(A, B, C) __builtin_amdgcn_mfma_f32_16x16x32_bf16((A), (B), (C), 0, 0, 0)

__launch_bounds__(512)
__global__ void stargnn_kernel(
    const float* __restrict__ x_feat,   // (B,N,FIN)
    const float* __restrict__ coords,   // (B,N,3)
    const float* __restrict__ mask,     // (B,N,1)
    const int*   __restrict__ centers,  // (B,)
    const float* __restrict__ nb1, const float* __restrict__ nb2,
    const float* __restrict__ eW1, const float* __restrict__ eb1,
    const float* __restrict__ eW2, const float* __restrict__ eb2,
    const float* __restrict__ rW1, const float* __restrict__ rb1,
    const float* __restrict__ rW2, const float* __restrict__ rb2,
    const unsigned short* __restrict__ wbf,  // ws: w1t @0, w2t @4096
    float* __restrict__ out)            // (B,FOUT)
{
    const int b   = blockIdx.x;
    const int tid = threadIdx.x;
    const int wv  = tid >> 6;     // wave 0..7
    const int wvc = wv & 3;       // column-pair group: cols 32*wvc .. +31
    const int rh  = wv >> 2;      // row half: rows rh*64 .. +63
    const int l   = tid & 63;
    const int lr  = l & 15;
    const int lg  = l >> 4;

    const int col0 = wvc * 32 + lr;        // first owned column
    const int col1 = wvc * 32 + 16 + lr;   // second owned column

    __shared__ __align__(16) unsigned short xbf[128 * 40];    // 10240 B
    __shared__ __align__(16) unsigned short h1bf[128 * 136];  // 34816 B (permuted cols)
    __shared__ __align__(16) float wns[NN];   // w_n*mask^2 (+ center delta)
    __shared__ float epart[NN];               // edge-MLP partial (terms 16..31)
    __shared__ float msgs[HH];
    __shared__ float part[2 * HH];            // cross-rh partials
    __shared__ float part4[4 * HH];           // readout split-K partials
    __shared__ float r1s[HH];

    const int c = centers[b];

    // ---- zero xbf once (cols 15..39 must stay 0) ----
    for (int i = tid; i < (128 * 40) / 2; i += 512)
        ((unsigned int*)xbf)[i] = 0u;

    // ---- edge MLP partial: all 8 waves, 16 terms each ----
    const int en = tid & 255;
    const int eh = tid >> 8;
    float es;
    {
        const float* cb = coords + (size_t)b * NN * 3;
        const float c0x = cb[c*3+0], c0y = cb[c*3+1], c0z = cb[c*3+2];
        const float dx = cb[en*3+0] - c0x;
        const float dy = cb[en*3+1] - c0y;
        const float dz = cb[en*3+2] - c0z;
        const float d  = sqrtf(dx*dx + dy*dy + dz*dz);
        es = (eh == 0) ? eb2[0] : 0.0f;
        #pragma unroll
        for (int i = 0; i < 16; ++i) {
            const int t = eh * 16 + i;
            float z = d * eW1[t] + eb1[t];
            es += silu_f(z) * eW2[t];
        }
        if (eh == 1) epart[en] = es;
    }
    __syncthreads();   // zerofill + epart ready

    // ---- finalize wns (waves 0..3) ----
    if (eh == 0) {
        const float m = mask[(size_t)b * NN + en];
        const float w = sigm_f(es + epart[en]);
        wns[en] = w * m * m + ((en == c) ? m : 0.0f);
    }

    // ---- bias-as-C-init vectors ----
    const float nb1c0 = nb1[col0], nb1c1 = nb1[col1];
    const float nb2c0 = nb2[col0], nb2c1 = nb2[col1];
    const f32x4 b1i0 = {nb1c0, nb1c0, nb1c0, nb1c0};
    const f32x4 b1i1 = {nb1c1, nb1c1, nb1c1, nb1c1};
    const f32x4 b2i0 = {nb2c0, nb2c0, nb2c0, nb2c0};
    const f32x4 b2i1 = {nb2c1, nb2c1, nb2c1, nb2c1};

    // ---- B-fragments (named registers, whole kernel) ----
    const short8v* w1tp = (const short8v*)wbf;            // [128][32]: idx = n*4 + lg
    const short8v* w2tp = (const short8v*)(wbf + 4096);   // [128][128] perm-k: idx = n*16 + kb*4 + lg
    const short8v b1f0 = w1tp[col0 * 4 + lg];
    const short8v b1f1 = w1tp[col1 * 4 + lg];
    const short8v b2f00 = w2tp[col0 * 16 + 0  + lg];
    const short8v b2f01 = w2tp[col0 * 16 + 4  + lg];
    const short8v b2f02 = w2tp[col0 * 16 + 8  + lg];
    const short8v b2f03 = w2tp[col0 * 16 + 12 + lg];
    const short8v b2f10 = w2tp[col1 * 16 + 0  + lg];
    const short8v b2f11 = w2tp[col1 * 16 + 4  + lg];
    const short8v b2f12 = w2tp[col1 * 16 + 8  + lg];
    const short8v b2f13 = w2tp[col1 * 16 + 12 + lg];

    float macc0 = 0.f, macc1 = 0.f;
    unsigned int* h1dw = (unsigned int*)h1bf;

    // ================= two halves of 128 nodes =================
    for (int half = 0; half < 2; ++half) {
        // ---- stage x -> bf16 [128][40] via cvt_pk (safe: all xbf readers have
        // passed the previous half's layer1->layer2 barrier) ----
        {
            const int node = tid >> 2;          // 0..127
            const int kq   = tid & 3;           // k-quad 0..3
            const float* xr = x_feat + ((size_t)b * NN + half * 128 + node) * FIN + kq * 4;
            const float f0 = xr[0];
            const float f1 = xr[1];
            const float f2 = xr[2];
            const float f3 = (kq < 3) ? xr[3] : 0.0f;   // k=15 pad
            const unsigned int p0 = cvt_pk_bf16(f0, f1);
            const unsigned int p1 = cvt_pk_bf16(f2, f3);
            unsigned int* dst = (unsigned int*)&xbf[node * 40 + kq * 4];
            dst[0] = p0;
            dst[1] = p1;
        }
        __syncthreads();   // xbf ready; (half1) also fences prev-half h1bf reads

        // ---- layer 1: h1 = silu(x @ nW1 + nb1) -> permuted h1bf ----
        #pragma unroll 1
        for (int mi = 0; mi < 4; ++mi) {
            const int mt = rh * 4 + mi;
            const short8v a = *(const short8v*)&xbf[(mt * 16 + lr) * 40 + lg * 8];
            f32x4 d0 = MFMA16(a, b1f0, b1i0);
            f32x4 d1 = MFMA16(a, b1f1, b1i1);
            #define H1W(r) { \
                const int row = mt * 16 + lg * 4 + (r); \
                h1dw[row * 68 + 16 * wvc + lr] = cvt_pk_bf16(silu_f(d0[r]), silu_f(d1[r])); }
            H1W(0) H1W(1) H1W(2) H1W(3)
            #undef H1W
        }
        __syncthreads();   // h1bf ready

        // ---- layer 2 MFMA + epilogue ----
        #pragma unroll 1
        for (int mi = 0; mi < 4; ++mi) {
            const int mt = rh * 4 + mi;
            const unsigned short* arow = &h1bf[(mt * 16 + lr) * 136 + lg * 8];
            const short8v a0 = *(const short8v*)(arow);
            const short8v a1 = *(const short8v*)(arow + 32);
            const short8v a2 = *(const short8v*)(arow + 64);
            const short8v a3 = *(const short8v*)(arow + 96);
            f32x4 acc0 = b2i0, acc1 = b2i1;
            acc0 = MFMA16(a0, b2f00, acc0);
            acc0 = MFMA16(a1, b2f01, acc0);
            acc0 = MFMA16(a2, b2f02, acc0);
            acc0 = MFMA16(a3, b2f03, acc0);
            acc1 = MFMA16(a0, b2f10, acc1);
            acc1 = MFMA16(a1, b2f11, acc1);
            acc1 = MFMA16(a2, b2f12, acc1);
            acc1 = MFMA16(a3, b2f13, acc1);

            const f32x4 mw4 = *(const f32x4*)&wns[half * 128 + mt * 16 + lg * 4];
            #define EPIR(r) { \
                macc0 += mw4[r] * silu_f(acc0[r]); \
                macc1 += mw4[r] * silu_f(acc1[r]); }
            EPIR(0) EPIR(1) EPIR(2) EPIR(3)
            #undef EPIR
        }
    }

    // ---- reduce msg: lanes (lg) via shfl, row-halves (rh) via LDS ----
    macc0 += __shfl_xor(macc0, 16);
    macc0 += __shfl_xor(macc0, 32);
    macc1 += __shfl_xor(macc1, 16);
    macc1 += __shfl_xor(macc1, 32);
    if (lg == 0) {
        part[rh * HH + col0] = macc0;
        part[rh * HH + col1] = macc1;
    }
    __syncthreads();

    if (tid < HH) msgs[tid] = part[tid] + part[HH + tid];
    __syncthreads();

    // ---- readout layer 1 (f32 VALU, split-K over 4 quarter groups) ----
    {
        const int j  = tid & 127;
        const int kq = tid >> 7;
        float acc = 0.f;
        #pragma unroll 8
        for (int k = kq * 32; k < kq * 32 + 32; ++k)
            acc += msgs[k] * rW1[k * HH + j];
        part4[kq * HH + j] = acc;
    }
    __syncthreads();
    if (tid < HH)
        r1s[tid] = silu_f(part4[tid] + part4[HH + tid] + part4[2 * HH + tid]
                          + part4[3 * HH + tid] + rb1[tid]);
    __syncthreads();

    // ---- final layer: 32 threads per output, shfl reduce ----
    if (tid < 32 * FOUT) {
        const int j  = tid >> 5;        // 0..5
        const int kk = tid & 31;        // 0..31
        float acc = 0.f;
        #pragma unroll
        for (int q = 0; q < 4; ++q) {
            const int k = kk * 4 + q;
            acc += r1s[k] * rW2[k * FOUT + j];
        }
        acc += __shfl_xor(acc, 1);
        acc += __shfl_xor(acc, 2);
        acc += __shfl_xor(acc, 4);
        acc += __shfl_xor(acc, 8);
        acc += __shfl_xor(acc, 16);
        if (kk == 0) out[(size_t)b * FOUT + j] = acc + rb2[j];
    }
}

extern "C" void kernel_launch(void* const* d_in, const int* in_sizes, int n_in,
                              void* d_out, int out_size, void* d_ws, size_t ws_size,
                              hipStream_t stream) {
    const float* x_feat = (const float*)d_in[0];
    const float* coords = (const float*)d_in[1];
    const float* mask   = (const float*)d_in[2];
    const int*   ctr    = (const int*)d_in[3];
    const float* nW1 = (const float*)d_in[4];
    const float* nb1 = (const float*)d_in[5];
    const float* nW2 = (const float*)d_in[6];
    const float* nb2 = (const float*)d_in[7];
    const float* eW1 = (const float*)d_in[8];
    const float* eb1 = (const float*)d_in[9];
    const float* eW2 = (const float*)d_in[10];
    const float* eb2 = (const float*)d_in[11];
    const float* rW1 = (const float*)d_in[12];
    const float* rb1 = (const float*)d_in[13];
    const float* rW2 = (const float*)d_in[14];
    const float* rb2 = (const float*)d_in[15];
    float* out = (float*)d_out;
    unsigned short* wbf = (unsigned short*)d_ws;

    prep_kernel<<<dim3(80), dim3(256), 0, stream>>>(nW1, nW2, wbf);
    stargnn_kernel<<<dim3(BB), dim3(512), 0, stream>>>(
        x_feat, coords, mask, ctr,
        nb1, nb2, eW1, eb1, eW2, eb2, rW1, rb1, rW2, rb2, wbf, out);
}